// Round 14
// baseline (125.335 us; speedup 1.0000x reference)
//
#include <hip/hip_runtime.h>
#include <hip/hip_bf16.h>

typedef short short8 __attribute__((ext_vector_type(8)));
typedef short short4_t __attribute__((ext_vector_type(4)));
typedef float floatx4 __attribute__((ext_vector_type(4)));
typedef unsigned short ushort_t;
typedef unsigned int uint32;

#define H 320
#define W 320
#define CG 16
#define NCH 64
#define HW (H * W)
#define CGP 20       // ushorts per LDS col (40B): writes 2-way max (free per m136)
#define HALFW 160

__device__ __forceinline__ ushort_t f2bf(float f) {
  unsigned u = __float_as_uint(f);
  return (ushort_t)((u + 0x7FFFu + ((u >> 16) & 1u)) >> 16);  // RNE (weights only)
}

// LDS-only barrier: does NOT drain vmcnt -> global loads/stores stay in flight.
__device__ __forceinline__ void barrier_lgkm() {
  asm volatile("s_waitcnt lgkmcnt(0)" ::: "memory");
  __builtin_amdgcn_s_barrier();
}

// Block: 256 thr = 4 waves; ring-6 LDS; swapped MFMA (r13).
// NEW: staging lane = col-QUAD -> dwordx4 loads (16B/lane, 1KB/inst), 16
// loads/thread/task. SHIFT4 % 4 == 0 and W % 4 == 0 => edge quads are fully
// in/out -> quad-uniform masks. LDS col permutation [cc][q][ic] (QW odd)
// keeps ds_writes conflict-free.
template<int G>
__device__ __forceinline__ void conv_group(
    const float* __restrict__ x, const float* __restrict__ wgt,
    const float* __restrict__ bias, float* __restrict__ out,
    ushort_t* tile, int bx) {
  constexpr int DIL   = (G == 0) ? 1 : (G == 1) ? 6 : (G == 2) ? 12 : 18;
  constexpr int S4    = (G == 0) ? 4 : (G == 1) ? 8 : (G == 2) ? 12 : 20;  // SHIFT, mult of 4
  constexpr int QW    = (G == 0) ? 43 : (G == 1) ? 45 : (G == 2) ? 47 : 51; // col-quads, odd
  constexpr int WH4   = 4 * QW;                 // 172/180/188/204 staged cols
  constexpr int KOFF4 = S4 - DIL;               // 3/2/0/2
  constexpr int WKS   = 16 * DIL;               // walks per group
  constexpr int RPW   = (H + DIL - 1) / DIL;
  constexpr int QT    = (RPW + 3) / 4;          // 80/14/7/5 tasks per walk
  constexpr int CPW   = (G == 0) ? 27 : (G == 1) ? 5 : (G == 2) ? 3 : 2;
  constexpr int L     = (QT + CPW - 1) / CPW;   // 3 tasks per chunk

  const int tid  = threadIdx.x;
  const int lane = tid & 63;
  const int wv   = tid >> 6;
  const int pxl = lane & 15, z = lane >> 4, icq = z & 1, zh = z >> 1;

  // ---- per-wave weight fragments (register gather; B-operand of swapped mfma)
  short8 aw[5];
#pragma unroll
  for (int t = 0; t < 5; ++t) {
    const int tp = 2 * t + zh;                  // k-octet map: tap=2t+(z>>1)
#pragma unroll
    for (int jj = 0; jj < 8; ++jj) {
      float v = 0.f;
      if (tp < 9) v = wgt[((size_t)(G * CG + pxl) * CG + icq * 8 + jj) * 9 + tp];
      aw[t][jj] = (short)f2bf(v);
    }
  }
  const float bb = bias[G * CG + pxl];          // oc = lane&15 (swapped C/D)

  // ---- decode block -> (walk, chunk) ----
  const int walk  = bx % WKS;
  const int chunk = bx / WKS;
  const int r  = walk % DIL;
  const int wb = ((walk / DIL) & 1) * HALFW;
  const int b  = walk / (2 * DIL);
  const int q0 = chunk * L;
  const int qend = (q0 + L < QT) ? q0 + L : QT;
  if (q0 >= qend) return;

  // ---- staging constants: lane = col-quad, wave = ch-quad ----
  const bool act   = lane < QW;
  const int  gq    = wb - S4 + 4 * lane;        // quad base global col (mult of 4)
  const bool cvld  = (gq >= 0) & (gq < W);      // whole quad in/out
  const int  gcl   = gq < 0 ? 0 : (gq > W - 4 ? W - 4 : gq);
  const float* chb = x + (size_t)(b * NCH + G * CG + 4 * wv) * HW;

  auto STAGER = [&](int rho, int slot) {        // one input row: 4x dwordx4
    const int yy = rho * DIL + r;
    const bool rv = (yy >= 0) & (yy < H);
    const int yyc = yy < 0 ? 0 : (yy >= H ? H - 1 : yy);
    const float* rowb = chb + (size_t)yyc * W + gcl;
    if (act) {
      const floatx4 p0 = *(const floatx4*)(rowb);
      const floatx4 p1 = *(const floatx4*)(rowb + HW);
      const floatx4 p2 = *(const floatx4*)(rowb + 2 * HW);
      const floatx4 p3 = *(const floatx4*)(rowb + 3 * HW);
      const bool m = rv & cvld;
      ushort_t* colp = tile + ((size_t)slot * WH4 + lane) * CGP + 4 * wv;
#pragma unroll
      for (int cc = 0; cc < 4; ++cc) {          // col 4*lane+cc -> lds idx cc*QW+lane
        const __hip_bfloat162 h01 = __float22bfloat162_rn(make_float2(p0[cc], p1[cc]));
        const __hip_bfloat162 h23 = __float22bfloat162_rn(make_float2(p2[cc], p3[cc]));
        uint2 pk;
        pk.x = m ? *(const uint32*)&h01 : 0u;
        pk.y = m ? *(const uint32*)&h23 : 0u;
        *(uint2*)(colp + (size_t)cc * QW * CGP) = pk;   // ds_write_b64
      }
    }
  };

  auto COMPUTE = [&](int q, int m6) {
    const int y = (4 * q + wv) * DIL + r;
    if (y >= H) return;
    // swapped C/D: lane&15 = oc, regs = 4 consecutive px
    float* outb = out + (size_t)(b * NCH + G * CG + pxl) * HW + (size_t)y * W + wb + 4 * z;
    const ushort_t* rowp[5];
#pragma unroll
    for (int t = 0; t < 5; ++t) {
      const int tp = 2 * t + zh;
      const int ky = tp < 9 ? tp / 3 : 0;
      const int kx = tp < 9 ? tp - ky * 3 : 0;
      int s = m6 + wv + ky; s -= (s >= 6) ? 6 : 0;     // ring slot of row wv+ky
      const int ct = pxl + kx * DIL + KOFF4;           // lds col
      const int idx0 = (ct & 3) * QW + (ct >> 2);      // permuted col index
      rowp[t] = tile + ((size_t)s * WH4 + idx0) * CGP + icq * 8;
    }
#pragma unroll 2
    for (int ti = 0; ti < HALFW / 16; ++ti) {
      floatx4 acc = {0.f, 0.f, 0.f, 0.f};
#pragma unroll
      for (int t = 0; t < 5; ++t) {
        const ushort_t* pf = rowp[t] + ti * 4 * CGP;   // +16 cols = +4 quads
        const short4_t lo = *(const short4_t*)pf;
        const short4_t hi = *(const short4_t*)(pf + 4);
        const short8 bf = {lo[0], lo[1], lo[2], lo[3], hi[0], hi[1], hi[2], hi[3]};
        acc = __builtin_amdgcn_mfma_f32_16x16x32_bf16(bf, aw[t], acc, 0, 0, 0);  // A=x, B=w
      }
      const floatx4 st = {acc[0] + bb, acc[1] + bb, acc[2] + bb, acc[3] + bb};
      *(floatx4*)(outb + ti * 16) = st;                // dwordx4, L2-merged (no nt)
    }
  };

  auto wrap6 = [](int v) { return v >= 6 ? v - 6 : v; };
  int m6 = (4 * q0 + 5) % 6;                    // slot of row 4q0-1

  // ---- prologue: stage 6 rows ----
#pragma unroll
  for (int j = 0; j < 6; ++j) STAGER(4 * q0 - 1 + j, wrap6(m6 + j));
  barrier_lgkm();

  // ---- task loop ----
#pragma unroll 1
  for (int q = q0; q < qend; ++q) {
    COMPUTE(q, m6);
    if (q + 1 < qend) {                         // block-uniform
      barrier_lgkm();                           // tile readers done (lgkm only)
#pragma unroll
      for (int j = 0; j < 4; ++j) STAGER(4 * q + 5 + j, wrap6(m6 + j));
      barrier_lgkm();                           // tile ready
      m6 = wrap6(m6 + 4);
    }
  }
}

extern "C" __global__ void __launch_bounds__(256, 3) conv_all(
    const float* __restrict__ x, const float* __restrict__ wgt,
    const float* __restrict__ bias, float* __restrict__ out) {
  extern __shared__ ushort_t lds[];
  const int bid = blockIdx.x;
  // fine-grained blocks (~8/CU) for tail balance: 576+576+480+432 = 2064
  if (bid < 576)       conv_group<3>(x, wgt, bias, out, lds, bid);         // 288 walks x 2
  else if (bid < 1152) conv_group<2>(x, wgt, bias, out, lds, bid - 576);   // 192 x 3
  else if (bid < 1632) conv_group<1>(x, wgt, bias, out, lds, bid - 1152);  // 96 x 5
  else                 conv_group<0>(x, wgt, bias, out, lds, bid - 1632);  // 16 x 27
}

extern "C" void kernel_launch(void* const* d_in, const int* in_sizes, int n_in,
                              void* d_out, int out_size, void* d_ws, size_t ws_size,
                              hipStream_t stream) {
  const float* x    = (const float*)d_in[0];
  const float* wgt  = (const float*)d_in[1];
  const float* bias = (const float*)d_in[2];
  float* out        = (float*)d_out;

  // dynamic LDS (G3): 6 * 204 * 20 * 2 = 48960 B -> 3 blocks/CU
  const size_t lds_bytes = (size_t)6 * 204 * CGP * 2;
  conv_all<<<dim3(2064), dim3(256), lds_bytes, stream>>>(x, wgt, bias, out);
}

// Round 15
// 115.919 us; speedup vs baseline: 1.0812x; 1.0812x over previous
//
#include <hip/hip_runtime.h>
#include <hip/hip_bf16.h>

typedef short short8 __attribute__((ext_vector_type(8)));
typedef short short4_t __attribute__((ext_vector_type(4)));
typedef float floatx4 __attribute__((ext_vector_type(4)));
typedef unsigned short ushort_t;
typedef unsigned int uint32;

#define H 320
#define W 320
#define CG 16
#define NCH 64
#define HW (H * W)
#define CGP 20       // ushorts per LDS col (40B): conflict-free frag reads (measured 0)
#define HALFW 160

__device__ __forceinline__ ushort_t f2bf(float f) {
  unsigned u = __float_as_uint(f);
  return (ushort_t)((u + 0x7FFFu + ((u >> 16) & 1u)) >> 16);  // RNE (weights only)
}

// LDS-only barrier: does NOT drain vmcnt -> global loads/stores stay in flight.
__device__ __forceinline__ void barrier_lgkm() {
  asm volatile("s_waitcnt lgkmcnt(0)" ::: "memory");
  __builtin_amdgcn_s_barrier();
}

// Block: 256 thr = 4 waves; ring-6 LDS row buffer; straight-line task loop.
// SWAPPED MFMA (r13 win): mfma(A=x_frag, B=w_frag) -> C/D has col(lane&15)=oc
// and regs = 4 CONSECUTIVE pixels -> epilogue = one global_store_dwordx4.
// r15 delta vs r13: plain store (no nontemporal) -> L2 write-merge, WRITE 237->205MB.
template<int G>
__device__ __forceinline__ void conv_group(
    const float* __restrict__ x, const float* __restrict__ wgt,
    const float* __restrict__ bias, float* __restrict__ out,
    ushort_t* lds, int bx) {
  constexpr int DIL   = (G == 0) ? 1 : (G == 1) ? 6 : (G == 2) ? 12 : 18;
  constexpr int KOFF  = DIL & 1;
  constexpr int SHIFT = DIL + KOFF;              // lds col c <-> global col wb + c - SHIFT
  constexpr int WH    = (HALFW + 2 * DIL + KOFF + 1) & ~1;  // 164/172/184/196
  constexpr int NP    = (WH + 63) / 64;          // 3/3/3/4
  constexpr int WKS   = 16 * DIL;                // walks = DIL * 2(wb) * 8(b)
  constexpr int RPW   = (H + DIL - 1) / DIL;
  constexpr int Q     = (RPW + 3) / 4;           // 80/14/7/5 tasks per walk
  constexpr int CPW   = (G == 0) ? 12 : (G == 1) ? 2 : 1;
  constexpr int L     = (Q + CPW - 1) / CPW;     // 7/7/7/5 tasks per chunk

  const int tid = threadIdx.x;
  ushort_t* tile = lds;                          // [6][WH][CGP]
  ushort_t* swt  = lds + 6 * WH * CGP;           // [5][4][16][8] w-frag table
  uint32* swt32  = (uint32*)swt;

  // ---- weight fragment table (once per block) ----
#pragma unroll
  for (int k = 0; k < 5; ++k) {
    const int s = tid + k * 256;
    const int jp = s & 3, oc = (s >> 2) & 15, zz = (s >> 6) & 3, t = s >> 8;
    const int tp = 2 * t + (zz >> 1);
    uint32 pk = 0;
    if (tp < 9) {
      const float* wp = wgt + ((size_t)(G * CG + oc) * CG + (zz & 1) * 8 + 2 * jp) * 9 + tp;
      pk = (uint32)f2bf(wp[0]) | ((uint32)f2bf(wp[9]) << 16);
    }
    swt32[s] = pk;
  }
  __syncthreads();

  const int lane = tid & 63;
  const int wv   = tid >> 6;
  const int z = lane >> 4, icq = z & 1, pxl = lane & 15;
  short8 aw[5];
#pragma unroll
  for (int t = 0; t < 5; ++t) aw[t] = *(const short8*)&swt[((t * 4 + z) * 16 + pxl) * 8];
  const float bb = bias[G * CG + pxl];           // oc = lane&15 in swapped layout

  // ---- decode block -> (walk, chunk) ----
  const int walk  = bx % WKS;
  const int chunk = bx / WKS;
  const int r  = walk % DIL;
  const int wb = ((walk / DIL) & 1) * HALFW;
  const int b  = walk / (2 * DIL);
  const int q0 = chunk * L;
  const int qend = (q0 + L < Q) ? q0 + L : Q;

  // ---- staging constants: thread = (col = lane, ch-quad = wv) ----
  bool zm[NP]; bool inb[NP]; int gofs[NP];
#pragma unroll
  for (int p = 0; p < NP; ++p) {
    const int c = 64 * p + lane;
    inb[p] = (c < WH);
    const int gc = wb + c - SHIFT;
    zm[p] = inb[p] & (gc >= 0) & (gc < W);
    gofs[p] = gc < 0 ? 0 : (gc >= W ? W - 1 : gc);
  }
  const float* chb = x + (size_t)(b * NCH + G * CG + 4 * wv) * HW;

  auto LOADR = [&](int rho, float (&rg)[NP][4]) {
    const int yy = rho * DIL + r;
    const int yyc = yy < 0 ? 0 : (yy >= H ? H - 1 : yy);
    const float* rp = chb + (size_t)yyc * W;
#pragma unroll
    for (int p = 0; p < NP; ++p)
#pragma unroll
      for (int k = 0; k < 4; ++k)
        rg[p][k] = rp[(size_t)k * HW + gofs[p]];   // 256B coalesced per inst
  };

  auto CVTR = [&](int rho, int slot, float (&rg)[NP][4]) {
    const int yy = rho * DIL + r;
    const bool rv = (yy >= 0) & (yy < H);
#pragma unroll
    for (int p = 0; p < NP; ++p) {
      const bool m = rv & zm[p];
      const __hip_bfloat162 h01 = __float22bfloat162_rn(make_float2(rg[p][0], rg[p][1]));
      const __hip_bfloat162 h23 = __float22bfloat162_rn(make_float2(rg[p][2], rg[p][3]));
      uint2 pk;
      pk.x = m ? *(const uint32*)&h01 : 0u;
      pk.y = m ? *(const uint32*)&h23 : 0u;
      if (inb[p]) {
        const int c = 64 * p + lane;
        *(uint2*)&tile[(size_t)(slot * WH + c) * CGP + wv * 4] = pk;  // ds_write_b64
      }
    }
  };

  auto COMPUTE = [&](int q, int m6) {
    const int y = (4 * q + wv) * DIL + r;
    if (y >= H) return;
    const int zh = z >> 1;
    // swapped C/D: lane&15 = oc, regs = px {4z..4z+3}
    float* outb = out + (size_t)(b * NCH + G * CG + pxl) * HW + (size_t)y * W + wb + 4 * z;
    const ushort_t* rowp[5];                 // statically indexed (unrolled t)
#pragma unroll
    for (int t = 0; t < 5; ++t) {
      const int tp = 2 * t + zh;
      const int ky = tp < 9 ? tp / 3 : 0;
      const int kx = tp < 9 ? tp - ky * 3 : 0;
      int s = m6 + wv + ky; s -= (s >= 6) ? 6 : 0;   // slot of row j = wv+ky
      rowp[t] = tile + (size_t)s * (WH * CGP) + (size_t)(pxl + kx * DIL + KOFF) * CGP + icq * 8;
    }
#pragma unroll 2
    for (int ti = 0; ti < HALFW / 16; ++ti) {
      floatx4 acc = {0.f, 0.f, 0.f, 0.f};
#pragma unroll
      for (int t = 0; t < 5; ++t) {
        const ushort_t* pf = rowp[t] + ti * 16 * CGP;
        const short4_t lo = *(const short4_t*)pf;
        const short4_t hi = *(const short4_t*)(pf + 4);
        const short8 bf = {lo[0], lo[1], lo[2], lo[3], hi[0], hi[1], hi[2], hi[3]};
        acc = __builtin_amdgcn_mfma_f32_16x16x32_bf16(bf, aw[t], acc, 0, 0, 0);  // A=x, B=w
      }
      const floatx4 st = {acc[0] + bb, acc[1] + bb, acc[2] + bb, acc[3] + bb};
      *(floatx4*)(outb + ti * 16) = st;      // plain dwordx4: L2 write-merge
    }
  };

  auto wrap6 = [](int v) { return v >= 6 ? v - 6 : v; };
  int m6 = (4 * q0 + 5) % 6;                 // slot of row rho = 4q-1 (ring-6)

  // ---- prologue: stage 6 rows ----
  {
    float ra[NP][4], rb[NP][4];
    LOADR(4 * q0 - 1, ra); LOADR(4 * q0 + 0, rb);
    CVTR(4 * q0 - 1, wrap6(m6 + 0), ra); CVTR(4 * q0 + 0, wrap6(m6 + 1), rb);
    LOADR(4 * q0 + 1, ra); LOADR(4 * q0 + 2, rb);
    CVTR(4 * q0 + 1, wrap6(m6 + 2), ra); CVTR(4 * q0 + 2, wrap6(m6 + 3), rb);
    LOADR(4 * q0 + 3, ra); LOADR(4 * q0 + 4, rb);
    CVTR(4 * q0 + 3, wrap6(m6 + 4), ra); CVTR(4 * q0 + 4, wrap6(m6 + 5), rb);
  }
  barrier_lgkm();

  // ---- task loop: straight-line body; final iteration peeled ----
#pragma unroll 1
  for (int q = q0; q < qend - 1; ++q) {
    float ra[NP][4], rb[NP][4], rc[NP][4], rd[NP][4];
    LOADR(4 * q + 5, ra); LOADR(4 * q + 6, rb);
    LOADR(4 * q + 7, rc); LOADR(4 * q + 8, rd);
    COMPUTE(q, m6);                          // prefetch drains under this
    barrier_lgkm();                          // tile readers done (lgkm only)
    CVTR(4 * q + 5, m6,            ra);
    CVTR(4 * q + 6, wrap6(m6 + 1), rb);
    CVTR(4 * q + 7, wrap6(m6 + 2), rc);
    CVTR(4 * q + 8, wrap6(m6 + 3), rd);
    barrier_lgkm();                          // tile ready for next task
    m6 = wrap6(m6 + 4);
  }
  COMPUTE(qend - 1, m6);                     // epilogue: no staging
}

extern "C" __global__ void __launch_bounds__(256, 3) conv_all(
    const float* __restrict__ x, const float* __restrict__ wgt,
    const float* __restrict__ bias, float* __restrict__ out) {
  extern __shared__ ushort_t lds[];
  const int bid = blockIdx.x;
  if (bid < 288)      conv_group<3>(x, wgt, bias, out, lds, bid);        // 288 blocks
  else if (bid < 480) conv_group<2>(x, wgt, bias, out, lds, bid - 288);  // 192
  else if (bid < 672) conv_group<1>(x, wgt, bias, out, lds, bid - 480);  // 192
  else                conv_group<0>(x, wgt, bias, out, lds, bid - 672);  // 192
}

extern "C" void kernel_launch(void* const* d_in, const int* in_sizes, int n_in,
                              void* d_out, int out_size, void* d_ws, size_t ws_size,
                              hipStream_t stream) {
  const float* x    = (const float*)d_in[0];
  const float* wgt  = (const float*)d_in[1];
  const float* bias = (const float*)d_in[2];
  float* out        = (float*)d_out;

  // dynamic LDS (max over groups, G3): 6*196*20*2 + 5120 = 52160 B -> 3 blocks/CU
  const size_t lds_bytes = (size_t)(6 * 196 * CGP + 5 * 4 * 16 * 8) * 2;
  conv_all<<<dim3(864), dim3(256), lds_bytes, stream>>>(x, wgt, bias, out);
}

// Round 16
// 101.268 us; speedup vs baseline: 1.2377x; 1.1447x over previous
//
#include <hip/hip_runtime.h>
#include <hip/hip_bf16.h>

typedef short short8 __attribute__((ext_vector_type(8)));
typedef short short4_t __attribute__((ext_vector_type(4)));
typedef float floatx4 __attribute__((ext_vector_type(4)));
typedef unsigned short ushort_t;
typedef unsigned int uint32;

#define H 320
#define W 320
#define CG 16
#define NCH 64
#define HW (H * W)
#define CGP 20       // ushorts per LDS col (40B): conflict-free frag reads (measured 0)
#define HALFW 160

__device__ __forceinline__ ushort_t f2bf(float f) {
  unsigned u = __float_as_uint(f);
  return (ushort_t)((u + 0x7FFFu + ((u >> 16) & 1u)) >> 16);  // RNE (weights only)
}

// LDS-only barrier: does NOT drain vmcnt -> global loads/stores stay in flight.
__device__ __forceinline__ void barrier_lgkm() {
  asm volatile("s_waitcnt lgkmcnt(0)" ::: "memory");
  __builtin_amdgcn_s_barrier();
}

// r16 = r13 (best known: swapped MFMA + nt dwordx4 store) + XCD-locality
// scheduling: task order [G][b][wb][r][chunk] (batch OUTERMOST) and
// i = (bid%8)*108 + bid/8 so each XCD gets 108 consecutive tasks -> its L2
// works on 1-3 batches instead of 8 (nt A/B r13/r15 proved L2-residency of x
// is the latency term).
template<int G>
__device__ __forceinline__ void conv_group(
    const float* __restrict__ x, const float* __restrict__ wgt,
    const float* __restrict__ bias, float* __restrict__ out,
    ushort_t* lds, int bx) {
  constexpr int DIL   = (G == 0) ? 1 : (G == 1) ? 6 : (G == 2) ? 12 : 18;
  constexpr int KOFF  = DIL & 1;
  constexpr int SHIFT = DIL + KOFF;              // lds col c <-> global col wb + c - SHIFT
  constexpr int WH    = (HALFW + 2 * DIL + KOFF + 1) & ~1;  // 164/172/184/196
  constexpr int NP    = (WH + 63) / 64;          // 3/3/3/4
  constexpr int RPW   = (H + DIL - 1) / DIL;
  constexpr int Q     = (RPW + 3) / 4;           // 80/14/7/5 tasks per walk
  constexpr int CPW   = (G == 0) ? 12 : (G == 1) ? 2 : 1;
  constexpr int L     = (Q + CPW - 1) / CPW;     // 7/7/7/5 tasks per chunk

  const int tid = threadIdx.x;
  ushort_t* tile = lds;                          // [6][WH][CGP]
  ushort_t* swt  = lds + 6 * WH * CGP;           // [5][4][16][8] w-frag table
  uint32* swt32  = (uint32*)swt;

  // ---- weight fragment table (once per block) ----
#pragma unroll
  for (int k = 0; k < 5; ++k) {
    const int s = tid + k * 256;
    const int jp = s & 3, oc = (s >> 2) & 15, zz = (s >> 6) & 3, t = s >> 8;
    const int tp = 2 * t + (zz >> 1);
    uint32 pk = 0;
    if (tp < 9) {
      const float* wp = wgt + ((size_t)(G * CG + oc) * CG + (zz & 1) * 8 + 2 * jp) * 9 + tp;
      pk = (uint32)f2bf(wp[0]) | ((uint32)f2bf(wp[9]) << 16);
    }
    swt32[s] = pk;
  }
  __syncthreads();

  const int lane = tid & 63;
  const int wv   = tid >> 6;
  const int z = lane >> 4, icq = z & 1, pxl = lane & 15;
  short8 aw[5];
#pragma unroll
  for (int t = 0; t < 5; ++t) aw[t] = *(const short8*)&swt[((t * 4 + z) * 16 + pxl) * 8];
  const float bb = bias[G * CG + pxl];           // oc = lane&15 in swapped layout

  // ---- decode: bx ordered [b][wb][r][chunk] (batch outermost) ----
  const int chunk = bx % CPW;
  const int t1 = bx / CPW;
  const int r  = t1 % DIL;
  const int t2 = t1 / DIL;
  const int wb = (t2 & 1) * HALFW;
  const int b  = t2 >> 1;
  const int q0 = chunk * L;
  const int qend = (q0 + L < Q) ? q0 + L : Q;

  // ---- staging constants: thread = (col = lane, ch-quad = wv) ----
  bool zm[NP]; bool inb[NP]; int gofs[NP];
#pragma unroll
  for (int p = 0; p < NP; ++p) {
    const int c = 64 * p + lane;
    inb[p] = (c < WH);
    const int gc = wb + c - SHIFT;
    zm[p] = inb[p] & (gc >= 0) & (gc < W);
    gofs[p] = gc < 0 ? 0 : (gc >= W ? W - 1 : gc);
  }
  const float* chb = x + (size_t)(b * NCH + G * CG + 4 * wv) * HW;

  auto LOADR = [&](int rho, float (&rg)[NP][4]) {
    const int yy = rho * DIL + r;
    const int yyc = yy < 0 ? 0 : (yy >= H ? H - 1 : yy);
    const float* rp = chb + (size_t)yyc * W;
#pragma unroll
    for (int p = 0; p < NP; ++p)
#pragma unroll
      for (int k = 0; k < 4; ++k)
        rg[p][k] = rp[(size_t)k * HW + gofs[p]];   // 256B coalesced per inst
  };

  auto CVTR = [&](int rho, int slot, float (&rg)[NP][4]) {
    const int yy = rho * DIL + r;
    const bool rv = (yy >= 0) & (yy < H);
#pragma unroll
    for (int p = 0; p < NP; ++p) {
      const bool m = rv & zm[p];
      const __hip_bfloat162 h01 = __float22bfloat162_rn(make_float2(rg[p][0], rg[p][1]));
      const __hip_bfloat162 h23 = __float22bfloat162_rn(make_float2(rg[p][2], rg[p][3]));
      uint2 pk;
      pk.x = m ? *(const uint32*)&h01 : 0u;
      pk.y = m ? *(const uint32*)&h23 : 0u;
      if (inb[p]) {
        const int c = 64 * p + lane;
        *(uint2*)&tile[(size_t)(slot * WH + c) * CGP + wv * 4] = pk;  // ds_write_b64
      }
    }
  };

  auto COMPUTE = [&](int q, int m6) {
    const int y = (4 * q + wv) * DIL + r;
    if (y >= H) return;
    const int zh = z >> 1;
    // swapped C/D: lane&15 = oc, regs = px {4z..4z+3}
    float* outb = out + (size_t)(b * NCH + G * CG + pxl) * HW + (size_t)y * W + wb + 4 * z;
    const ushort_t* rowp[5];                 // statically indexed (unrolled t)
#pragma unroll
    for (int t = 0; t < 5; ++t) {
      const int tp = 2 * t + zh;
      const int ky = tp < 9 ? tp / 3 : 0;
      const int kx = tp < 9 ? tp - ky * 3 : 0;
      int s = m6 + wv + ky; s -= (s >= 6) ? 6 : 0;   // slot of row j = wv+ky
      rowp[t] = tile + (size_t)s * (WH * CGP) + (size_t)(pxl + kx * DIL + KOFF) * CGP + icq * 8;
    }
#pragma unroll 2
    for (int ti = 0; ti < HALFW / 16; ++ti) {
      floatx4 acc = {0.f, 0.f, 0.f, 0.f};
#pragma unroll
      for (int t = 0; t < 5; ++t) {
        const ushort_t* pf = rowp[t] + ti * 16 * CGP;
        const short4_t lo = *(const short4_t*)pf;
        const short4_t hi = *(const short4_t*)(pf + 4);
        const short8 bf = {lo[0], lo[1], lo[2], lo[3], hi[0], hi[1], hi[2], hi[3]};
        acc = __builtin_amdgcn_mfma_f32_16x16x32_bf16(bf, aw[t], acc, 0, 0, 0);  // A=x, B=w
      }
      floatx4 st = {acc[0] + bb, acc[1] + bb, acc[2] + bb, acc[3] + bb};
      __builtin_nontemporal_store(st, (floatx4*)(outb + ti * 16));  // nt: no L2 pollution (r13/r15 A/B)
    }
  };

  auto wrap6 = [](int v) { return v >= 6 ? v - 6 : v; };
  int m6 = (4 * q0 + 5) % 6;                 // slot of row rho = 4q-1 (ring-6)

  // ---- prologue: stage 6 rows ----
  {
    float ra[NP][4], rb[NP][4];
    LOADR(4 * q0 - 1, ra); LOADR(4 * q0 + 0, rb);
    CVTR(4 * q0 - 1, wrap6(m6 + 0), ra); CVTR(4 * q0 + 0, wrap6(m6 + 1), rb);
    LOADR(4 * q0 + 1, ra); LOADR(4 * q0 + 2, rb);
    CVTR(4 * q0 + 1, wrap6(m6 + 2), ra); CVTR(4 * q0 + 2, wrap6(m6 + 3), rb);
    LOADR(4 * q0 + 3, ra); LOADR(4 * q0 + 4, rb);
    CVTR(4 * q0 + 3, wrap6(m6 + 4), ra); CVTR(4 * q0 + 4, wrap6(m6 + 5), rb);
  }
  barrier_lgkm();

  // ---- task loop: straight-line body; final iteration peeled ----
#pragma unroll 1
  for (int q = q0; q < qend - 1; ++q) {
    float ra[NP][4], rb[NP][4], rc[NP][4], rd[NP][4];
    LOADR(4 * q + 5, ra); LOADR(4 * q + 6, rb);
    LOADR(4 * q + 7, rc); LOADR(4 * q + 8, rd);
    COMPUTE(q, m6);                          // prefetch drains under this
    barrier_lgkm();                          // tile readers done (lgkm only)
    CVTR(4 * q + 5, m6,            ra);
    CVTR(4 * q + 6, wrap6(m6 + 1), rb);
    CVTR(4 * q + 7, wrap6(m6 + 2), rc);
    CVTR(4 * q + 8, wrap6(m6 + 3), rd);
    barrier_lgkm();                          // tile ready for next task
    m6 = wrap6(m6 + 4);
  }
  COMPUTE(qend - 1, m6);                     // epilogue: no staging
}

extern "C" __global__ void __launch_bounds__(256, 3) conv_all(
    const float* __restrict__ x, const float* __restrict__ wgt,
    const float* __restrict__ bias, float* __restrict__ out) {
  extern __shared__ ushort_t lds[];
  // XCD-locality: 864 = 8 x 108; dispatch round-robins bid%8 across XCDs, so
  // i = (bid%8)*108 + bid/8 gives each XCD 108 CONSECUTIVE tasks (bijective).
  const int bid = blockIdx.x;
  const int i = (bid & 7) * 108 + (bid >> 3);
  if (i < 288)      conv_group<3>(x, wgt, bias, out, lds, i);        // 288 tasks
  else if (i < 480) conv_group<2>(x, wgt, bias, out, lds, i - 288);  // 192
  else if (i < 672) conv_group<1>(x, wgt, bias, out, lds, i - 480);  // 192
  else              conv_group<0>(x, wgt, bias, out, lds, i - 672);  // 192
}

extern "C" void kernel_launch(void* const* d_in, const int* in_sizes, int n_in,
                              void* d_out, int out_size, void* d_ws, size_t ws_size,
                              hipStream_t stream) {
  const float* x    = (const float*)d_in[0];
  const float* wgt  = (const float*)d_in[1];
  const float* bias = (const float*)d_in[2];
  float* out        = (float*)d_out;

  // dynamic LDS (max over groups, G3): 6*196*20*2 + 5120 = 52160 B -> 3 blocks/CU
  const size_t lds_bytes = (size_t)(6 * 196 * CGP + 5 * 4 * 16 * 8) * 2;
  conv_all<<<dim3(864), dim3(256), lds_bytes, stream>>>(x, wgt, bias, out);
}

// Round 17
// 96.921 us; speedup vs baseline: 1.2932x; 1.0448x over previous
//
#include <hip/hip_runtime.h>
#include <hip/hip_bf16.h>

typedef short short8 __attribute__((ext_vector_type(8)));
typedef short short4_t __attribute__((ext_vector_type(4)));
typedef float floatx4 __attribute__((ext_vector_type(4)));
typedef unsigned short ushort_t;
typedef unsigned int uint32;

#define H 320
#define W 320
#define CG 16
#define NCH 64
#define HW (H * W)
#define CGP 20       // ushorts per LDS col (40B): conflict-free frag reads (measured 0)
#define HALFW 160

__device__ __forceinline__ ushort_t f2bf(float f) {
  unsigned u = __float_as_uint(f);
  return (ushort_t)((u + 0x7FFFu + ((u >> 16) & 1u)) >> 16);  // RNE (weights only)
}

// LDS-only barrier: does NOT drain vmcnt -> global loads/stores stay in flight.
__device__ __forceinline__ void barrier_lgkm() {
  asm volatile("s_waitcnt lgkmcnt(0)" ::: "memory");
  __builtin_amdgcn_s_barrier();
}

// r17 = r16 body (swapped MFMA + nt dwordx4 store + ring-6) with a BALANCED
// XCD map: task order [b][G][wb][r][chunk] (batch outermost, groups
// interleaved). Per batch = 108 blocks (G3:36,G2:24,G1:24,G0:24); xcd=bid&7,
// j=bid>>3 -> XCD k runs exactly batch k: perfect work balance + max x-locality
// (r16's group-pure slices put all heavy G0 blocks on 2 XCDs -> straggle).
template<int G>
__device__ __forceinline__ void conv_group(
    const float* __restrict__ x, const float* __restrict__ wgt,
    const float* __restrict__ bias, float* __restrict__ out,
    ushort_t* lds, int b, int bx) {
  constexpr int DIL   = (G == 0) ? 1 : (G == 1) ? 6 : (G == 2) ? 12 : 18;
  constexpr int KOFF  = DIL & 1;
  constexpr int SHIFT = DIL + KOFF;              // lds col c <-> global col wb + c - SHIFT
  constexpr int WH    = (HALFW + 2 * DIL + KOFF + 1) & ~1;  // 164/172/184/196
  constexpr int NP    = (WH + 63) / 64;          // 3/3/3/4
  constexpr int RPW   = (H + DIL - 1) / DIL;
  constexpr int Q     = (RPW + 3) / 4;           // 80/14/7/5 tasks per walk
  constexpr int CPW   = (G == 0) ? 12 : (G == 1) ? 2 : 1;
  constexpr int L     = (Q + CPW - 1) / CPW;     // 7/7/7/5 tasks per chunk

  const int tid = threadIdx.x;
  ushort_t* tile = lds;                          // [6][WH][CGP]
  ushort_t* swt  = lds + 6 * WH * CGP;           // [5][4][16][8] w-frag table
  uint32* swt32  = (uint32*)swt;

  // ---- weight fragment table (once per block) ----
#pragma unroll
  for (int k = 0; k < 5; ++k) {
    const int s = tid + k * 256;
    const int jp = s & 3, oc = (s >> 2) & 15, zz = (s >> 6) & 3, t = s >> 8;
    const int tp = 2 * t + (zz >> 1);
    uint32 pk = 0;
    if (tp < 9) {
      const float* wp = wgt + ((size_t)(G * CG + oc) * CG + (zz & 1) * 8 + 2 * jp) * 9 + tp;
      pk = (uint32)f2bf(wp[0]) | ((uint32)f2bf(wp[9]) << 16);
    }
    swt32[s] = pk;
  }
  __syncthreads();

  const int lane = tid & 63;
  const int wv   = tid >> 6;
  const int z = lane >> 4, icq = z & 1, pxl = lane & 15;
  short8 aw[5];
#pragma unroll
  for (int t = 0; t < 5; ++t) aw[t] = *(const short8*)&swt[((t * 4 + z) * 16 + pxl) * 8];
  const float bb = bias[G * CG + pxl];           // oc = lane&15 in swapped layout

  // ---- decode group-local bx -> (wb, r, chunk); b passed in (= XCD) ----
  const int chunk = bx % CPW;
  const int t1 = bx / CPW;
  const int r  = t1 % DIL;
  const int wb = (t1 / DIL) * HALFW;             // t1/DIL in {0,1}
  const int q0 = chunk * L;
  const int qend = (q0 + L < Q) ? q0 + L : Q;

  // ---- staging constants: thread = (col = lane, ch-quad = wv) ----
  bool zm[NP]; bool inb[NP]; int gofs[NP];
#pragma unroll
  for (int p = 0; p < NP; ++p) {
    const int c = 64 * p + lane;
    inb[p] = (c < WH);
    const int gc = wb + c - SHIFT;
    zm[p] = inb[p] & (gc >= 0) & (gc < W);
    gofs[p] = gc < 0 ? 0 : (gc >= W ? W - 1 : gc);
  }
  const float* chb = x + (size_t)(b * NCH + G * CG + 4 * wv) * HW;

  auto LOADR = [&](int rho, float (&rg)[NP][4]) {
    const int yy = rho * DIL + r;
    const int yyc = yy < 0 ? 0 : (yy >= H ? H - 1 : yy);
    const float* rp = chb + (size_t)yyc * W;
#pragma unroll
    for (int p = 0; p < NP; ++p)
#pragma unroll
      for (int k = 0; k < 4; ++k)
        rg[p][k] = rp[(size_t)k * HW + gofs[p]];   // 256B coalesced per inst
  };

  auto CVTR = [&](int rho, int slot, float (&rg)[NP][4]) {
    const int yy = rho * DIL + r;
    const bool rv = (yy >= 0) & (yy < H);
#pragma unroll
    for (int p = 0; p < NP; ++p) {
      const bool m = rv & zm[p];
      const __hip_bfloat162 h01 = __float22bfloat162_rn(make_float2(rg[p][0], rg[p][1]));
      const __hip_bfloat162 h23 = __float22bfloat162_rn(make_float2(rg[p][2], rg[p][3]));
      uint2 pk;
      pk.x = m ? *(const uint32*)&h01 : 0u;
      pk.y = m ? *(const uint32*)&h23 : 0u;
      if (inb[p]) {
        const int c = 64 * p + lane;
        *(uint2*)&tile[(size_t)(slot * WH + c) * CGP + wv * 4] = pk;  // ds_write_b64
      }
    }
  };

  auto COMPUTE = [&](int q, int m6) {
    const int y = (4 * q + wv) * DIL + r;
    if (y >= H) return;
    const int zh = z >> 1;
    // swapped C/D: lane&15 = oc, regs = px {4z..4z+3}
    float* outb = out + (size_t)(b * NCH + G * CG + pxl) * HW + (size_t)y * W + wb + 4 * z;
    const ushort_t* rowp[5];                 // statically indexed (unrolled t)
#pragma unroll
    for (int t = 0; t < 5; ++t) {
      const int tp = 2 * t + zh;
      const int ky = tp < 9 ? tp / 3 : 0;
      const int kx = tp < 9 ? tp - ky * 3 : 0;
      int s = m6 + wv + ky; s -= (s >= 6) ? 6 : 0;   // slot of row j = wv+ky
      rowp[t] = tile + (size_t)s * (WH * CGP) + (size_t)(pxl + kx * DIL + KOFF) * CGP + icq * 8;
    }
#pragma unroll 2
    for (int ti = 0; ti < HALFW / 16; ++ti) {
      floatx4 acc = {0.f, 0.f, 0.f, 0.f};
#pragma unroll
      for (int t = 0; t < 5; ++t) {
        const ushort_t* pf = rowp[t] + ti * 16 * CGP;
        const short4_t lo = *(const short4_t*)pf;
        const short4_t hi = *(const short4_t*)(pf + 4);
        const short8 bf = {lo[0], lo[1], lo[2], lo[3], hi[0], hi[1], hi[2], hi[3]};
        acc = __builtin_amdgcn_mfma_f32_16x16x32_bf16(bf, aw[t], acc, 0, 0, 0);  // A=x, B=w
      }
      floatx4 st = {acc[0] + bb, acc[1] + bb, acc[2] + bb, acc[3] + bb};
      __builtin_nontemporal_store(st, (floatx4*)(outb + ti * 16));  // nt (r13/r15 A/B)
    }
  };

  auto wrap6 = [](int v) { return v >= 6 ? v - 6 : v; };
  int m6 = (4 * q0 + 5) % 6;                 // slot of row rho = 4q-1 (ring-6)

  // ---- prologue: stage 6 rows ----
  {
    float ra[NP][4], rb[NP][4];
    LOADR(4 * q0 - 1, ra); LOADR(4 * q0 + 0, rb);
    CVTR(4 * q0 - 1, wrap6(m6 + 0), ra); CVTR(4 * q0 + 0, wrap6(m6 + 1), rb);
    LOADR(4 * q0 + 1, ra); LOADR(4 * q0 + 2, rb);
    CVTR(4 * q0 + 1, wrap6(m6 + 2), ra); CVTR(4 * q0 + 2, wrap6(m6 + 3), rb);
    LOADR(4 * q0 + 3, ra); LOADR(4 * q0 + 4, rb);
    CVTR(4 * q0 + 3, wrap6(m6 + 4), ra); CVTR(4 * q0 + 4, wrap6(m6 + 5), rb);
  }
  barrier_lgkm();

  // ---- task loop: straight-line body; final iteration peeled ----
#pragma unroll 1
  for (int q = q0; q < qend - 1; ++q) {
    float ra[NP][4], rb[NP][4], rc[NP][4], rd[NP][4];
    LOADR(4 * q + 5, ra); LOADR(4 * q + 6, rb);
    LOADR(4 * q + 7, rc); LOADR(4 * q + 8, rd);
    COMPUTE(q, m6);                          // prefetch drains under this
    barrier_lgkm();                          // tile readers done (lgkm only)
    CVTR(4 * q + 5, m6,            ra);
    CVTR(4 * q + 6, wrap6(m6 + 1), rb);
    CVTR(4 * q + 7, wrap6(m6 + 2), rc);
    CVTR(4 * q + 8, wrap6(m6 + 3), rd);
    barrier_lgkm();                          // tile ready for next task
    m6 = wrap6(m6 + 4);
  }
  COMPUTE(qend - 1, m6);                     // epilogue: no staging
}

extern "C" __global__ void __launch_bounds__(256, 3) conv_all(
    const float* __restrict__ x, const float* __restrict__ wgt,
    const float* __restrict__ bias, float* __restrict__ out) {
  extern __shared__ ushort_t lds[];
  // Balanced XCD map: xcd = bid&7 = batch; j = bid>>3 indexes the batch's 108
  // blocks ordered [G3(36) | G2(24) | G1(24) | G0(24)], each [wb][r][chunk].
  const int bid = blockIdx.x;
  const int b = bid & 7;
  const int j = bid >> 3;
  if (j < 36)      conv_group<3>(x, wgt, bias, out, lds, b, j);       // 2*18*1
  else if (j < 60) conv_group<2>(x, wgt, bias, out, lds, b, j - 36);  // 2*12*1
  else if (j < 84) conv_group<1>(x, wgt, bias, out, lds, b, j - 60);  // 2*6*2
  else             conv_group<0>(x, wgt, bias, out, lds, b, j - 84);  // 2*1*12
}

extern "C" void kernel_launch(void* const* d_in, const int* in_sizes, int n_in,
                              void* d_out, int out_size, void* d_ws, size_t ws_size,
                              hipStream_t stream) {
  const float* x    = (const float*)d_in[0];
  const float* wgt  = (const float*)d_in[1];
  const float* bias = (const float*)d_in[2];
  float* out        = (float*)d_out;

  // dynamic LDS (max over groups, G3): 6*196*20*2 + 5120 = 52160 B -> 3 blocks/CU
  const size_t lds_bytes = (size_t)(6 * 196 * CGP + 5 * 4 * 16 * 8) * 2;
  conv_all<<<dim3(864), dim3(256), lds_bytes, stream>>>(x, wgt, bias, out);
}